// Round 6
// baseline (80.142 us; speedup 1.0000x reference)
//
#include <hip/hip_runtime.h>
#include <math.h>

constexpr int BN  = 8192;        // batch
constexpr int TPB = 1024;        // one block, 16 waves
constexpr int RPT = BN / TPB;    // 8 rows per thread
constexpr int NB  = 4096;        // t-buckets (floor(t*4096) is exact & monotone)
constexpr int BPT = NB / TPB;    // 4 buckets per thread
#define EPSF 1e-7f

// Single-kernel CombinedSurvLoss via counting-sort + bucket suffix sums.
// risk in [-4,0] => er=exp(risk) in [e^-4,1], so masked-LSE needs no max
// shift: lse_i = log( bucket_suffix[b_i+1] + sum_{same bucket, t_j>t_i} er_j ).
__global__ __launch_bounds__(1024)
void surv_kernel(const float4* __restrict__ outputs4,
                 const int*    __restrict__ y,
                 const float*  __restrict__ t,
                 const int*    __restrict__ c,
                 float*        __restrict__ out) {
    __shared__ float  s_t [BN];        // 32 KB  bucket-sorted t
    __shared__ float  s_er[BN];        // 32 KB  bucket-sorted er
    __shared__ int    bstart[NB + 1];  // 16 KB  bucket start offsets
    __shared__ int    bcur  [NB];      // 16 KB  histogram, then scatter cursor
    __shared__ double bsuf  [NB + 1];  // 32 KB  inclusive suffix of bucket sums
    __shared__ double dred[16 * 3];
    __shared__ int    iwave[16];
    __shared__ double dwave[16];

    const int tid  = threadIdx.x;
    const int lane = tid & 63;
    const int wav  = tid >> 6;

    // ---- Phase A: zero histogram ----
    #pragma unroll
    for (int k = 0; k < BPT; ++k) bcur[tid * BPT + k] = 0;
    __syncthreads();

    // ---- Phase B: per-row compute (NLL, risk, er, bucket) + histogram ----
    float tr[RPT], err[RPT], rkr[RPT];
    int   br[RPT];
    int   cbits = 0;
    double nll = 0.0;
    #pragma unroll
    for (int k = 0; k < RPT; ++k) {
        int r = tid + k * TPB;
        float4 h = outputs4[r];
        float hz0 = 1.f / (1.f + __expf(-h.x));
        float hz1 = 1.f / (1.f + __expf(-h.y));
        float hz2 = 1.f / (1.f + __expf(-h.z));
        float hz3 = 1.f / (1.f + __expf(-h.w));
        float s0 = 1.f - hz0;
        float s1 = s0 * (1.f - hz1);
        float s2 = s1 * (1.f - hz2);
        float s3 = s2 * (1.f - hz3);
        float risk = -(s0 + s1 + s2 + s3);
        int yi = y[r], ci = c[r];
        float s_prev = (yi == 0) ? 1.f : (yi == 1) ? s0 : (yi == 2) ? s1 : s2;
        float h_this = (yi == 0) ? hz0 : (yi == 1) ? hz1 : (yi == 2) ? hz2 : hz3;
        float s_this = (yi == 0) ? s0  : (yi == 1) ? s1  : (yi == 2) ? s2  : s3;
        float cf = (float)ci;
        nll += (double)(-(1.f - cf) * (__logf(fmaxf(s_prev, EPSF)) + __logf(fmaxf(h_this, EPSF)))
                        - cf * __logf(fmaxf(s_this, EPSF)));        // ALPHA == 0
        float tv = t[r];
        int b = (int)(tv * (float)NB);                // exact: *2^12
        b = (b < 0) ? 0 : (b > NB - 1 ? NB - 1 : b);
        tr[k] = tv; rkr[k] = risk; err[k] = __expf(risk); br[k] = b;
        cbits |= (ci != 0 ? 1 : 0) << k;
        atomicAdd(&bcur[b], 1);
    }
    __syncthreads();

    // ---- Phase C: exclusive prefix scan hist -> bstart (+ cursor copy) ----
    int h0[BPT]; int tsum = 0;
    #pragma unroll
    for (int k = 0; k < BPT; ++k) { h0[k] = bcur[tid * BPT + k]; tsum += h0[k]; }
    int incl = tsum;
    #pragma unroll
    for (int off = 1; off < 64; off <<= 1) {
        int v = __shfl_up(incl, off);
        if (lane >= off) incl += v;
    }
    if (lane == 63) iwave[wav] = incl;        // wave total
    __syncthreads();
    if (wav == 0 && lane < 16) {
        int x = iwave[lane];
        int in2 = x;
        #pragma unroll
        for (int off = 1; off < 16; off <<= 1) {
            int v = __shfl_up(in2, off);
            if (lane >= off) in2 += v;
        }
        iwave[lane] = in2 - x;                // exclusive over earlier waves
    }
    __syncthreads();
    int base = iwave[wav] + (incl - tsum);    // exclusive across all threads
    #pragma unroll
    for (int k = 0; k < BPT; ++k) {
        int b = tid * BPT + k;
        bstart[b] = base;
        bcur[b]   = base;                     // scatter cursor
        base += h0[k];
    }
    if (tid == 0) { bstart[NB] = BN; bsuf[NB] = 0.0; }
    __syncthreads();

    // ---- Phase D: scatter rows into bucket order ----
    #pragma unroll
    for (int k = 0; k < RPT; ++k) {
        int pos = atomicAdd(&bcur[br[k]], 1);
        s_t [pos] = tr[k];
        s_er[pos] = err[k];
    }
    __syncthreads();

    // ---- Phase E: bucket sums + inclusive suffix scan (f64) ----
    double bs[BPT]; double dtot = 0.0;
    #pragma unroll
    for (int k = 0; k < BPT; ++k) {
        int b = tid * BPT + k;
        double s = 0.0;
        for (int p = bstart[b]; p < bstart[b + 1]; ++p) s += (double)s_er[p];
        bs[k] = s; dtot += s;
    }
    double dincl = dtot;                      // inclusive suffix within wave
    #pragma unroll
    for (int off = 1; off < 64; off <<= 1) {
        double v = __shfl_down(dincl, off);
        if (lane + off < 64) dincl += v;
    }
    if (lane == 0) dwave[wav] = dincl;        // wave total
    __syncthreads();
    if (wav == 0 && lane < 16) {
        double x = dwave[lane];
        double in2 = x;
        #pragma unroll
        for (int off = 1; off < 16; off <<= 1) {
            double v = __shfl_down(in2, off);
            if (lane + off < 16) in2 += v;
        }
        dwave[lane] = in2 - x;                // suffix over later waves
    }
    __syncthreads();
    double dabove = dwave[wav] + (dincl - dtot);   // strictly-after this thread
    #pragma unroll
    for (int k = BPT - 1; k >= 0; --k) {      // high bucket -> low
        dabove += bs[k];
        bsuf[tid * BPT + k] = dabove;         // inclusive suffix
    }
    __syncthreads();

    // ---- Phase F: per-row rank term ----
    double rsum = 0.0, rcnt = 0.0;
    #pragma unroll
    for (int k = 0; k < RPT; ++k) {
        if (((cbits >> k) & 1) == 0) {        // fc_mask2: c == 0
            int b = br[k];
            double s = bsuf[b + 1];           // all strictly-higher buckets
            float tv = tr[k];
            int e = bstart[b + 1];
            for (int p = bstart[b]; p < e; ++p)
                if (s_t[p] > tv) s += (double)s_er[p];   // exact strict ties
            if (s > 0.0) {                    // any(mask)
                rsum += (double)(__logf((float)s) - rkr[k]);
                rcnt += 1.0;
            }
        }
    }

    // ---- Phase G: block reduce + output ----
    #pragma unroll
    for (int off = 32; off; off >>= 1) {
        nll  += __shfl_down(nll,  off);
        rsum += __shfl_down(rsum, off);
        rcnt += __shfl_down(rcnt, off);
    }
    if (lane == 0) { dred[wav * 3] = nll; dred[wav * 3 + 1] = rsum; dred[wav * 3 + 2] = rcnt; }
    __syncthreads();
    if (tid == 0) {
        double a = 0.0, b2 = 0.0, d = 0.0;
        #pragma unroll
        for (int w = 0; w < 16; ++w) { a += dred[w*3]; b2 += dred[w*3+1]; d += dred[w*3+2]; }
        double rank = (d > 0.0) ? (b2 / fmax(d, 1.0)) : 0.0;
        out[0] = (float)(a / (double)BN + 0.5 * rank);
    }
}

extern "C" void kernel_launch(void* const* d_in, const int* in_sizes, int n_in,
                              void* d_out, int out_size, void* d_ws, size_t ws_size,
                              hipStream_t stream) {
    const float4* outputs4 = (const float4*)d_in[0];
    const int*    y        = (const int*)d_in[1];
    const float*  t        = (const float*)d_in[2];
    const int*    c        = (const int*)d_in[3];
    float*        out      = (float*)d_out;

    surv_kernel<<<1, TPB, 0, stream>>>(outputs4, y, t, c, out);
}